// Round 16
// baseline (360.900 us; speedup 1.0000x reference)
//
#include <hip/hip_runtime.h>
#include <math.h>

// MinVQVAE1D forward. Plain-bf16 MFMA GEMMs + codebook-decoder factorization.
// Dual-grid dispatches: A=enc1||t3 (+zdisc zero-fill half), B=enc2||t4
// (+zero-fill half), C=enc3||xpT. Scores epilogue = argmin partials only.
// argmin+gather fused. 7 dispatches total.
// N=16384, D=1024, H=1024, L=256, K=4096.
// out = [x_pred (N*D) f32 | z_discrete 0/1 f32 (N*K) | loss (1)]

#define MB (1024ULL * 1024ULL)

typedef __attribute__((ext_vector_type(8))) short s16x8;
typedef __attribute__((ext_vector_type(4))) float f32x4;

__device__ __forceinline__ ushort f2bf(float f) {
    unsigned u = __float_as_uint(f);
    u += 0x7fffu + ((u >> 16) & 1u);
    return (ushort)(u >> 16);
}
__device__ __forceinline__ float bf2f(ushort h) {
    return __uint_as_float(((unsigned)h) << 16);
}
__device__ __forceinline__ float gelu_f(float v) {
    return 0.5f * v * (1.0f + erff(v * 0.70710678118654752f));
}
__device__ __forceinline__ void gload16(const void* g, void* l) {
    __builtin_amdgcn_global_load_lds(
        (const __attribute__((address_space(1))) void*)g,
        (__attribute__((address_space(3))) void*)l, 16, 0, 0);
}

// ---------------------------------------------------------------------------
// Merged prep: x->bf16 | pool->bf16 | colnorm | 6 weight transposes (bf16).
__device__ __forceinline__ void conv_body(const float* __restrict__ in,
                                          ushort* __restrict__ out,
                                          int n8, int vb, int nB)
{
    for (int i = vb * 256 + threadIdx.x; i < n8; i += nB * 256) {
        const float4 v0 = *(const float4*)(in + (size_t)i * 8);
        const float4 v1 = *(const float4*)(in + (size_t)i * 8 + 4);
        s16x8 h;
        h[0] = f2bf(v0.x); h[1] = f2bf(v0.y); h[2] = f2bf(v0.z); h[3] = f2bf(v0.w);
        h[4] = f2bf(v1.x); h[5] = f2bf(v1.y); h[6] = f2bf(v1.z); h[7] = f2bf(v1.w);
        *(s16x8*)(out + (size_t)i * 8) = h;
    }
}

__global__ __launch_bounds__(256)
void prep_all(const float* __restrict__ x, ushort* __restrict__ xb,
              const float* __restrict__ pool, ushort* __restrict__ poolb,
              float* __restrict__ cn,
              const float* __restrict__ ew1, ushort* __restrict__ w1,
              const float* __restrict__ ew2, ushort* __restrict__ w2,
              const float* __restrict__ ew3, ushort* __restrict__ w3,
              const float* __restrict__ dw1, ushort* __restrict__ v1,
              const float* __restrict__ dw2, ushort* __restrict__ v2,
              const float* __restrict__ dw3, ushort* __restrict__ v3)
{
    __shared__ float tile[32][33];
    const int b = blockIdx.x;
    const int tid = threadIdx.x;

    if (b < 2048) {                     // x: 16384x1024 -> bf16
        conv_body(x, xb, 16384 * 1024 / 8, b, 2048);
        return;
    }
    if (b < 2560) {                     // pool: 4096x256 -> bf16 (already B^T)
        conv_body(pool, poolb, 4096 * 256 / 8, b - 2048, 512);
        return;
    }
    if (b < 3584) {                     // colnorm: ||e_k||^2, 4 rows/block
        const int r = (b - 2560) * 4 + (tid >> 6);
        const int lane = tid & 63;
        float4 v = *(const float4*)(pool + (size_t)r * 256 + lane * 4);
        float s = v.x * v.x + v.y * v.y + v.z * v.z + v.w * v.w;
        #pragma unroll
        for (int o = 32; o > 0; o >>= 1) s += __shfl_down(s, o);
        if (lane == 0) cn[r] = s;
        return;
    }

    const float* in; ushort* out; int Kd, Nn, vb;
    if (b < 4608)      { in = ew1; out = w1; Kd = 1024; Nn = 1024; vb = b - 3584; }
    else if (b < 5632) { in = ew2; out = w2; Kd = 1024; Nn = 1024; vb = b - 4608; }
    else if (b < 5888) { in = ew3; out = w3; Kd = 1024; Nn = 256;  vb = b - 5632; }
    else if (b < 6144) { in = dw1; out = v1; Kd = 256;  Nn = 1024; vb = b - 5888; }
    else if (b < 7168) { in = dw2; out = v2; Kd = 1024; Nn = 1024; vb = b - 6144; }
    else               { in = dw3; out = v3; Kd = 1024; Nn = 1024; vb = b - 7168; }

    const int nxw = Nn / 32;
    const int n0 = (vb % nxw) * 32, k0 = (vb / nxw) * 32;
    const int tx = tid & 31, ty = tid >> 5;
    #pragma unroll
    for (int r = 0; r < 4; r++)
        tile[ty + r * 8][tx] = in[(size_t)(k0 + ty + r * 8) * Nn + n0 + tx];
    __syncthreads();
    #pragma unroll
    for (int r = 0; r < 4; r++) {
        const float v = tile[tx][ty + r * 8];
        out[(size_t)(n0 + ty + r * 8) * Kd + k0 + tx] = f2bf(v);
    }
}

// ---------------------------------------------------------------------------
// 256x256-tile body (proven): 512 thr (8 waves 2x4), 128x64/wave, 2 LDS bufs
// x 64KB, depth-1 prefetch, XCD swizzle within its sub-grid. BK=64.
// EPI: 1=gelu(+bias) bf16 out, 3=VQ argmin partials.
template<int EPI>
__device__ __forceinline__ void big_body(
    ushort* smem, int bflat, int nx, int ny,
    const ushort* __restrict__ A, const ushort* __restrict__ B,
    const float* __restrict__ bias, int Kd, int Nn,
    ushort* __restrict__ Cu,
    float* __restrict__ pval, int* __restrict__ pidx)
{
    constexpr int BUFS = 512 * 64;                  // 64KB per buffer

    const int tid = threadIdx.x;
    const int wave = tid >> 6, lane = tid & 63;

    const int nwg = nx * ny;
    const int wgid = (bflat & 7) * (nwg >> 3) + (bflat >> 3);
    const int bx = wgid % nx, by = wgid / nx;

    const int m0 = by * 256, n0 = bx * 256;
    const int wr = wave >> 2, wc = wave & 3;
    const int fcol = lane & 15, kgrp = lane >> 4;
    const int NT = Kd / 64;
    const int rs = Kd * 2;

    const int srow = lane >> 3;
    const int sswz = ((lane & 7) ^ srow) << 4;
    const char* Abase = (const char*)A + (size_t)m0 * rs;
    const char* Bbase = (const char*)B + (size_t)n0 * rs;

    f32x4 acc[8][4];
    #pragma unroll
    for (int m = 0; m < 8; m++)
        #pragma unroll
        for (int n = 0; n < 4; n++)
            acc[m][n] = (f32x4){0.f, 0.f, 0.f, 0.f};

    auto STAGE = [&](int buf, int t) {
        ushort* dst = smem + buf * BUFS;
        const size_t kb = (size_t)t * 128;
        #pragma unroll
        for (int g = 0; g < 4; g++) {
            const int rb = g * 64 + wave * 8;
            gload16(Abase + (size_t)(rb + srow) * rs + kb + sswz, dst + rb * 64);
            gload16(Bbase + (size_t)(rb + srow) * rs + kb + sswz,
                    dst + (256 + rb) * 64);
        }
    };
    auto LD = [&](int buf, int r, int u) -> s16x8 {
        return *(const s16x8*)(smem + buf * BUFS + r * 64 + ((u ^ (r & 7)) << 3));
    };

    STAGE(0, 0);
    for (int t = 0; t < NT; ++t) {
        asm volatile("s_waitcnt vmcnt(0)" ::: "memory");
        __builtin_amdgcn_s_barrier();
        if (t + 1 < NT) STAGE((t + 1) & 1, t + 1);
        const int buf = t & 1;
        s16x8 b2[4][2];
        #pragma unroll
        for (int n = 0; n < 4; n++) {
            const int r = 256 + wc * 64 + n * 16 + fcol;
            #pragma unroll
            for (int ks = 0; ks < 2; ks++) b2[n][ks] = LD(buf, r, ks * 4 + kgrp);
        }
        #pragma unroll
        for (int h = 0; h < 2; h++) {
            s16x8 a2[4][2];
            #pragma unroll
            for (int i = 0; i < 4; i++) {
                const int r = wr * 128 + (h * 4 + i) * 16 + fcol;
                #pragma unroll
                for (int ks = 0; ks < 2; ks++) a2[i][ks] = LD(buf, r, ks * 4 + kgrp);
            }
            __builtin_amdgcn_s_setprio(1);
            #pragma unroll
            for (int i = 0; i < 4; i++)
                #pragma unroll
                for (int n = 0; n < 4; n++)
                    #pragma unroll
                    for (int ks = 0; ks < 2; ks++)
                        acc[h * 4 + i][n] = __builtin_amdgcn_mfma_f32_16x16x32_bf16(
                            a2[i][ks], b2[n][ks], acc[h * 4 + i][n], 0, 0, 0);
            __builtin_amdgcn_s_setprio(0);
        }
    }
    __builtin_amdgcn_sched_barrier(0);

    int colg[4];
    float bcol[4];
    #pragma unroll
    for (int n = 0; n < 4; n++) {
        colg[n] = n0 + wc * 64 + n * 16 + fcol;
        bcol[n] = bias[colg[n]];
    }

    if constexpr (EPI == 1) {
        #pragma unroll
        for (int m = 0; m < 8; m++)
            #pragma unroll
            for (int v = 0; v < 4; v++) {
                const int row = m0 + wr * 128 + m * 16 + kgrp * 4 + v;
                #pragma unroll
                for (int n = 0; n < 4; n++) {
                    float val = gelu_f(acc[m][n][v] + bcol[n]);
                    Cu[(size_t)row * Nn + colg[n]] = f2bf(val);
                }
            }
    } else if constexpr (EPI == 3) {
        __syncthreads();
        float* sv = (float*)smem;            // [4][256]
        int*   si = (int*)(sv + 1024);
        #pragma unroll
        for (int m = 0; m < 8; m++)
            #pragma unroll
            for (int v = 0; v < 4; v++) {
                float best = INFINITY;
                int bidx = 0x7fffffff;
                #pragma unroll
                for (int n = 0; n < 4; n++) {
                    float sc = bcol[n] - 2.0f * acc[m][n][v];
                    if (sc < best || (sc == best && colg[n] < bidx)) { best = sc; bidx = colg[n]; }
                }
                #pragma unroll
                for (int d = 1; d < 16; d <<= 1) {
                    float ov = __shfl_xor(best, d, 64);
                    int   oi = __shfl_xor(bidx, d, 64);
                    if (ov < best || (ov == best && oi < bidx)) { best = ov; bidx = oi; }
                }
                if (fcol == 0) {
                    const int rl = wr * 128 + m * 16 + kgrp * 4 + v;
                    sv[wc * 256 + rl] = best;
                    si[wc * 256 + rl] = bidx;
                }
            }
        __syncthreads();
        if (tid < 256) {
            float v0 = sv[tid];
            int   i0 = si[tid];
            #pragma unroll
            for (int c = 1; c < 4; c++) {
                float v1 = sv[c * 256 + tid];
                int   i1 = si[c * 256 + tid];
                if (v1 < v0 || (v1 == v0 && i1 < i0)) { v0 = v1; i0 = i1; }
            }
            pval[(size_t)(m0 + tid) * nx + bx] = v0;
            pidx[(size_t)(m0 + tid) * nx + bx] = i0;
        }
    }
}

// ---------------------------------------------------------------------------
// 128x128-tile body (proven): waves 2x4 (64x32/wave), 3 bufs, distance-2
// prefetch, counted vmcnt(4). EPI: 0=+bias bf16, 1=gelu bf16, 2=sigmoid f32.
template<int EPI>
__device__ __forceinline__ void s128_body(
    ushort* smem, int bflat, int nx, int ny,
    const ushort* __restrict__ A, const ushort* __restrict__ B,
    const float* __restrict__ bias, int Kd, int Nn,
    ushort* __restrict__ Cu, float* __restrict__ Cf)
{
    constexpr int BUFS = 256 * 64;                  // 32KB per buffer

    const int tid = threadIdx.x;
    const int wave = tid >> 6, lane = tid & 63;

    const int nwg = nx * ny;
    const int wgid = (bflat & 7) * (nwg >> 3) + (bflat >> 3);
    const int bx = wgid % nx, by = wgid / nx;

    const int m0 = by * 128, n0 = bx * 128;
    const int wr = wave >> 2, wc = wave & 3;
    const int fcol = lane & 15, kgrp = lane >> 4;
    const int NT = Kd / 64;
    const int rs = Kd * 2;

    const int srow = lane >> 3;
    const int sswz = ((lane & 7) ^ srow) << 4;
    const char* Abase = (const char*)A + (size_t)m0 * rs;
    const char* Bbase = (const char*)B + (size_t)n0 * rs;

    f32x4 acc[4][2];
    #pragma unroll
    for (int m = 0; m < 4; m++)
        #pragma unroll
        for (int n = 0; n < 2; n++)
            acc[m][n] = (f32x4){0.f, 0.f, 0.f, 0.f};

    auto STAGE = [&](int buf, int t) {
        ushort* dst = smem + buf * BUFS;
        const size_t kb = (size_t)t * 128;
        #pragma unroll
        for (int g = 0; g < 2; g++) {
            const int rb = g * 64 + wave * 8;
            gload16(Abase + (size_t)(rb + srow) * rs + kb + sswz, dst + rb * 64);
            gload16(Bbase + (size_t)(rb + srow) * rs + kb + sswz,
                    dst + (128 + rb) * 64);
        }
    };
    auto LD = [&](int buf, int r, int u) -> s16x8 {
        return *(const s16x8*)(smem + buf * BUFS + r * 64 + ((u ^ (r & 7)) << 3));
    };

    STAGE(0, 0);
    STAGE(1, 1);
    for (int t = 0; t < NT; ++t) {
        if (t + 1 < NT) asm volatile("s_waitcnt vmcnt(4)" ::: "memory");
        else            asm volatile("s_waitcnt vmcnt(0)" ::: "memory");
        __builtin_amdgcn_s_barrier();
        if (t + 2 < NT) STAGE((t + 2) % 3, t + 2);
        const int buf = t % 3;
        s16x8 a2[4][2], b2[2][2];
        #pragma unroll
        for (int m = 0; m < 4; m++) {
            const int r = wr * 64 + m * 16 + fcol;
            #pragma unroll
            for (int ks = 0; ks < 2; ks++) a2[m][ks] = LD(buf, r, ks * 4 + kgrp);
        }
        #pragma unroll
        for (int n = 0; n < 2; n++) {
            const int r = 128 + wc * 32 + n * 16 + fcol;
            #pragma unroll
            for (int ks = 0; ks < 2; ks++) b2[n][ks] = LD(buf, r, ks * 4 + kgrp);
        }
        __builtin_amdgcn_s_setprio(1);
        #pragma unroll
        for (int m = 0; m < 4; m++)
            #pragma unroll
            for (int n = 0; n < 2; n++)
                #pragma unroll
                for (int ks = 0; ks < 2; ks++)
                    acc[m][n] = __builtin_amdgcn_mfma_f32_16x16x32_bf16(
                        a2[m][ks], b2[n][ks], acc[m][n], 0, 0, 0);
        __builtin_amdgcn_s_setprio(0);
    }
    __builtin_amdgcn_sched_barrier(0);

    #pragma unroll
    for (int n = 0; n < 2; n++) {
        const int col = n0 + wc * 32 + n * 16 + fcol;
        const float bc = bias[col];
        #pragma unroll
        for (int m = 0; m < 4; m++)
            #pragma unroll
            for (int v = 0; v < 4; v++) {
                const int row = m0 + wr * 64 + m * 16 + kgrp * 4 + v;
                float val = acc[m][n][v] + bc;
                if constexpr (EPI == 0) {
                    Cu[(size_t)row * Nn + col] = f2bf(val);
                } else if constexpr (EPI == 1) {
                    Cu[(size_t)row * Nn + col] = f2bf(gelu_f(val));
                } else {
                    Cf[(size_t)row * Nn + col] = 1.0f / (1.0f + expf(-val));
                }
            }
    }
}

// ---------------------------------------------------------------------------
// Dual dispatch kernels. gemm_dual_b1 additionally zero-fills 16 rows of
// zdisc per block (134MB per launch, hidden under the GEMM's MFMA phase).
__global__ __launch_bounds__(512, 2)
void gemm_dual_b1(const ushort* Ab, const ushort* Bb, const float* biasb,
                  int Kdb, int Nnb, ushort* Cub, int nxb, int nyb,
                  const ushort* As, const ushort* Bs, const float* biass,
                  int Kds, int Nns, ushort* Cus, int nxs, int nys,
                  float* zd, int zrow0)
{
    extern __shared__ ushort smem[];
    const int nbig = nxb * nyb;
    if ((int)blockIdx.x < nbig)
        big_body<1>(smem, blockIdx.x, nxb, nyb, Ab, Bb, biasb, Kdb, Nnb, Cub,
                    nullptr, nullptr);
    else
        s128_body<1>(smem, blockIdx.x - nbig, nxs, nys, As, Bs, biass,
                     Kds, Nns, Cus, nullptr);
    // zdisc zero-fill: 16 rows x 4096 f32 per block, contiguous f32x4 streams.
    f32x4* p = (f32x4*)(zd + (size_t)(zrow0 + blockIdx.x * 16) * 4096);
    const f32x4 z4 = (f32x4){0.f, 0.f, 0.f, 0.f};
    const int tid = threadIdx.x;
    #pragma unroll
    for (int j = 0; j < 32; j++)
        __builtin_nontemporal_store(z4, p + j * 512 + tid);
}

__global__ __launch_bounds__(512, 2)
void gemm_dual_128(const ushort* A0, const ushort* B0, const float* bias0,
                   int Kd0, int Nn0, ushort* Cu0, int nx0, int ny0,
                   const ushort* A1, const ushort* B1, const float* bias1,
                   int Kd1, int Nn1, float* Cf1, int nx1, int ny1)
{
    extern __shared__ ushort smem[];
    const int n0 = nx0 * ny0;
    if ((int)blockIdx.x < n0)
        s128_body<0>(smem, blockIdx.x, nx0, ny0, A0, B0, bias0, Kd0, Nn0,
                     Cu0, nullptr);
    else
        s128_body<2>(smem, blockIdx.x - n0, nx1, ny1, A1, B1, bias1,
                     Kd1, Nn1, nullptr, Cf1);
}

// scores: standalone big kernel, EPI=3 (argmin partials)
__global__ __launch_bounds__(512, 2)
void gemm_scores(const ushort* A, const ushort* B, const float* bias,
                 int Kd, int Nn, int nx, int ny,
                 float* pval, int* pidx)
{
    extern __shared__ ushort smem[];
    big_body<3>(smem, blockIdx.x, nx, ny, A, B, bias, Kd, Nn,
                nullptr, pval, pidx);
}

// ---------------------------------------------------------------------------
// Fused: reduce nblk partials -> kbest; scatter 1.0 into pre-zeroed zdisc;
// VQ partial; gather x_pred row from xpT + per-row SSE. 4 rows/block.
__global__ __launch_bounds__(256)
void argmin_gather(const float* __restrict__ pval, const int* __restrict__ pidx,
                   int nblk, const ushort* __restrict__ zE,
                   const float* __restrict__ pool,
                   float* __restrict__ zdisc,
                   const float* __restrict__ xpT, const float* __restrict__ x,
                   float* __restrict__ xpred,
                   float* __restrict__ vqP, float* __restrict__ sseP)
{
    const int t = threadIdx.x;
    const int r = blockIdx.x * 4 + (t >> 6);
    const int l = t & 63;

    float best = INFINITY;
    int bi = 0x7fffffff;
    if (l < nblk) {
        best = pval[(size_t)r * nblk + l];
        bi = pidx[(size_t)r * nblk + l];
    }
    #pragma unroll
    for (int d = 32; d > 0; d >>= 1) {
        float ov = __shfl_xor(best, d, 64);
        int   oi = __shfl_xor(bi, d, 64);
        if (ov < best || (ov == best && oi < bi)) { best = ov; bi = oi; }
    }
    const int kbest = bi;

    if (l == 0) zdisc[(size_t)r * 4096 + kbest] = 1.0f;

    // VQ partial: ||z_e - pool[kbest]||^2 (f32 pool, bf16 z_e)
    const float4 pz = *(const float4*)(pool + (size_t)kbest * 256 + l * 4);
    const ushort4 zh = *(const ushort4*)(zE + (size_t)r * 256 + l * 4);
    float d0 = bf2f(zh.x) - pz.x;
    float d1 = bf2f(zh.y) - pz.y;
    float d2 = bf2f(zh.z) - pz.z;
    float d3 = bf2f(zh.w) - pz.w;
    float svq = d0 * d0 + d1 * d1 + d2 * d2 + d3 * d3;

    // x_pred gather + SSE
    const float* src = xpT + (size_t)kbest * 1024;
    const float* xr  = x + (size_t)r * 1024;
    float* dst = xpred + (size_t)r * 1024;
    float s = 0.0f;
    #pragma unroll
    for (int j = 0; j < 4; j++) {
        const int c = (j * 64 + l) * 4;
        f32x4 v = *(const f32x4*)(src + c);
        const float4 xv = *(const float4*)(xr + c);
        __builtin_nontemporal_store(v, (f32x4*)(dst + c));
        float e0 = xv.x - v[0], e1 = xv.y - v[1];
        float e2 = xv.z - v[2], e3 = xv.w - v[3];
        s += e0 * e0 + e1 * e1 + e2 * e2 + e3 * e3;
    }
    #pragma unroll
    for (int o = 32; o > 0; o >>= 1) {
        s   += __shfl_xor(s, o, 64);
        svq += __shfl_xor(svq, o, 64);
    }
    if (l == 0) { sseP[r] = s; vqP[r] = svq; }
}

__global__ __launch_bounds__(256)
void loss_final(const float* __restrict__ sseP, int nP,
                const float* __restrict__ vqP, int nV,
                float* __restrict__ out)
{
    int tid = threadIdx.x;
    float sx = 0.0f, svq = 0.0f;
    for (int i = tid; i < nP; i += 256) sx += sseP[i];
    for (int i = tid; i < nV; i += 256) svq += vqP[i];
    __shared__ float a[256], b[256];
    a[tid] = sx; b[tid] = svq;
    __syncthreads();
    for (int s = 128; s > 0; s >>= 1) {
        if (tid < s) { a[tid] += a[tid + s]; b[tid] += b[tid + s]; }
        __syncthreads();
    }
    if (tid == 0) out[0] = (a[0] + 1.25f * b[0]) / 16384.0f;
}

// ---------------------------------------------------------------------------
extern "C" void kernel_launch(void* const* d_in, const int* in_sizes, int n_in,
                              void* d_out, int out_size, void* d_ws, size_t ws_size,
                              hipStream_t stream)
{
    const float* x    = (const float*)d_in[0];
    const float* pool = (const float*)d_in[1];
    const float* ew1  = (const float*)d_in[2];
    const float* eb1  = (const float*)d_in[3];
    const float* ew2  = (const float*)d_in[4];
    const float* eb2  = (const float*)d_in[5];
    const float* ew3  = (const float*)d_in[6];
    const float* eb3  = (const float*)d_in[7];
    const float* dw1  = (const float*)d_in[8];
    const float* db1  = (const float*)d_in[9];
    const float* dw2  = (const float*)d_in[10];
    const float* db2  = (const float*)d_in[11];
    const float* dw3  = (const float*)d_in[12];
    const float* db3  = (const float*)d_in[13];

    const int N = 16384, D = 1024, H = 1024, L = 256, K = 4096;

    float* out   = (float*)d_out;
    float* xpred = out;
    float* zdisc = out + (size_t)N * D;
    float* lossp = zdisc + (size_t)N * K;

    char* ws = (char*)d_ws;
    ushort* xb    = (ushort*)(ws + 0 * MB);    // 32MB x bf16
    ushort* h1    = (ushort*)(ws + 32 * MB);   // 32MB
    ushort* h2    = (ushort*)(ws + 64 * MB);   // 32MB
    ushort* zE    = (ushort*)(ws + 96 * MB);   // 8MB
    ushort* poolb = (ushort*)(ws + 104 * MB);  // 2MB
    ushort* w1    = (ushort*)(ws + 106 * MB);  // 2MB
    ushort* w2    = (ushort*)(ws + 108 * MB);  // 2MB
    ushort* w3    = (ushort*)(ws + 110 * MB);  // 0.5MB
    ushort* v1    = (ushort*)(ws + 111 * MB);  // 0.5MB
    ushort* v2    = (ushort*)(ws + 112 * MB);  // 2MB
    ushort* v3    = (ushort*)(ws + 114 * MB);  // 2MB
    ushort* t3    = (ushort*)(ws + 116 * MB);  // 8MB  codebook h3 table
    ushort* t4    = (ushort*)(ws + 124 * MB);  // 8MB  codebook h4 table
    float*  xpT   = (float*)(ws + 132 * MB);   // 16MB codebook x_pred table
    float*  cn    = (float*)(ws + 148 * MB);   // 16KB
    float*  pv    = (float*)(ws + 149 * MB);   // 1MB (16384 x 16)
    int*    pi    = (int*)(ws + 150 * MB);     // 1MB
    float*  vqP   = (float*)(ws + 151 * MB);   // 64KB
    float*  sxP   = (float*)(ws + 152 * MB);   // 64KB

    const int SH_BIG = 2 * (512 * 64) * 2;     // 131072 B
    const int SH_128 = 3 * (256 * 64) * 2;     // 98304 B
    (void)hipFuncSetAttribute((const void*)gemm_dual_b1,
        hipFuncAttributeMaxDynamicSharedMemorySize, SH_BIG);
    (void)hipFuncSetAttribute((const void*)gemm_dual_128,
        hipFuncAttributeMaxDynamicSharedMemorySize, SH_128);
    (void)hipFuncSetAttribute((const void*)gemm_scores,
        hipFuncAttributeMaxDynamicSharedMemorySize, SH_BIG);

    dim3 blk(256), gblk(512);

    // merged prep (x/pool bf16 convert, colnorm, 6 weight transposes)
    prep_all<<<8192, blk, 0, stream>>>(x, xb, pool, poolb, cn,
                                       ew1, w1, ew2, w2, ew3, w3,
                                       dw1, v1, dw2, v2, dw3, v3);

    // A: enc1 || t3, + zdisc rows [0, 8192) zero-fill
    gemm_dual_b1<<<512, gblk, SH_BIG, stream>>>(
        xb, w1, eb1, D, H, h1, H / 256, N / 256,
        poolb, v1, db1, L, H, t3, H / 128, K / 128,
        zdisc, 0);

    // B: enc2 || t4, + zdisc rows [8192, 16384) zero-fill
    gemm_dual_b1<<<512, gblk, SH_BIG, stream>>>(
        h1, w2, eb2, H, H, h2, H / 256, N / 256,
        t3, v2, db2, H, H, t4, H / 128, K / 128,
        zdisc, 8192);

    // C: enc3 (z_e) || xpT = sigmoid(t4@dw3+b)
    gemm_dual_128<<<512, gblk, SH_128, stream>>>(
        h2, w3, eb3, H, L, zE, L / 128, N / 128,
        t4, v3, db3, H, D, xpT, D / 128, K / 128);

    // VQ scores + fused per-block argmin (zdisc already zeroed)
    gemm_scores<<<(K / 256) * (N / 256), gblk, SH_BIG, stream>>>(
        zE, poolb, cn, L, K, K / 256, N / 256, pv, pi);

    // argmin finalize + one-hot scatter + x_pred gather + loss partials
    argmin_gather<<<N / 4, blk, 0, stream>>>(pv, pi, K / 256, zE, pool,
                                             zdisc, xpT, x, xpred, vqP, sxP);

    loss_final<<<1, blk, 0, stream>>>(sxP, N, vqP, N, lossp);
}